// Round 4
// baseline (177.760 us; speedup 1.0000x reference)
//
#include <hip/hip_runtime.h>
#include <math.h>

#define TOPK 13
#define PI_F 3.14159265358979323846f
#define K1_THREADS 512

typedef unsigned int u32;
typedef unsigned long long u64;

// monotone float -> uint mapping matching XLA total order
__device__ __forceinline__ u32 ford(float f) {
    u32 u = __float_as_uint(f);
    return (u & 0x80000000u) ? ~u : (u | 0x80000000u);
}
__device__ __forceinline__ float funord(u32 o) {
    u32 u = (o & 0x80000000u) ? (o & 0x7FFFFFFFu) : ~o;
    return __uint_as_float(u);
}

__device__ __forceinline__ float iou_fn(float4 g, float4 p) {
    float ltx = fmaxf(g.x, p.x), lty = fmaxf(g.y, p.y);
    float rbx = fminf(g.z, p.z), rby = fminf(g.w, p.w);
    float inter = fmaxf(rbx - ltx, 0.0f) * fmaxf(rby - lty, 0.0f);
    float a1 = fmaxf(g.z - g.x, 0.0f) * fmaxf(g.w - g.y, 0.0f);
    float a2 = fmaxf(p.z - p.x, 0.0f) * fmaxf(p.w - p.y, 0.0f);
    return inter / (((a1 + a2) - inter) + 1e-9f);
}

struct RowParams { float av, bar, offc, mx, mn; };

__device__ __forceinline__ RowParams row_params(float4 g) {
    float w = g.z - g.x, h = g.w - g.y;
    float ar = w / (h + 1e-5f);
    float ia = 1.0f / ar;
    RowParams rp;
    rp.av = ia / (2.0f - ia);
    rp.bar = 2.0f / ar;
    rp.offc = PI_F * (1.0f - 2.0f / (2.0f * ar));
    rp.mx = 0.5f + 0.5f * cosf(rp.offc);
    rp.mn = 0.5f + 0.5f * cosf(rp.bar * 90.0f / 180.0f * PI_F + rp.offc);
    return rp;
}

__device__ __forceinline__ float ang_measure(const RowParams& rp, float theta) {
    float cfv = 0.5f + 0.5f * cosf(rp.bar * theta / 180.0f * PI_F + rp.offc);
    float r = (cfv - rp.mn) / (rp.mx - rp.mn) * (1.0f - rp.av) + rp.av;
    return isnan(r) ? 0.0f : r;
}

// align in exact reference op order: (s**1 * iou**5) * ang**3, left-assoc
__device__ __forceinline__ float align_fn(float s, float iou, float r) {
    float iou2 = iou * iou;
    float iou5 = (iou2 * iou2) * iou;
    float r3 = (r * r) * r;
    return (s * iou5) * r3;
}

__global__ void k0_init(int* cnt, int* assign1, u32* pam, u32* pov, int BA, int BN) {
    int t = blockIdx.x * blockDim.x + threadIdx.x;
    if (t < BA) { cnt[t] = 0; assign1[t] = -1; }
    if (t < BN) { pam[t] = 0x80000000u; pov[t] = 0x80000000u; } // ord(+0.0f)
}

__global__ __launch_bounds__(K1_THREADS)
void k1_topk(const float* __restrict__ scores, const float* __restrict__ pbox,
             const float* __restrict__ pang, const float* __restrict__ anc,
             const int* __restrict__ glab, const float* __restrict__ gbox,
             const float* __restrict__ gang, const float* __restrict__ mgt,
             int* __restrict__ cnt, int* __restrict__ assign1,
             int bs, int A, int n, int C) {
    int j = blockIdx.x;
    // XCD clustering: blocks of the same batch land on the same XCD (j % 8 == b % 8)
    int b = j % bs;
    int i = j / bs;
    int bi = b * n + i;
    int tid = threadIdx.x;

    float mg = mgt[bi];
    if (!(mg > 0.0f)) return;   // masked row contributes nothing

    float4 g = ((const float4*)gbox)[bi];
    int lab = glab[bi];
    float ga = gang[bi];
    RowParams rp = row_params(g);

    const float4* pb = ((const float4*)pbox) + (size_t)b * A;
    const float* pa = pang + (size_t)b * A;
    const float2* ac = (const float2*)anc;
    const float* sc = scores + (size_t)b * A * C + lab;

    u64 arr[TOPK];
#pragma unroll
    for (int jj = 0; jj < TOPK; jj++) arr[jj] = 0ull;
    u64 zkey = 0ull;  // thread's lowest-index exact-+0 candidate

    for (int a = tid; a < A; a += K1_THREADS) {
        float4 p = pb[a];
        float iou = iou_fn(g, p);
        float2 apt = ac[a];
        float mnv = fminf(fminf(apt.x - g.x, apt.y - g.y), fminf(g.z - apt.x, g.w - apt.y));
        bool inGt = mnv > 1e-9f;
        bool hot = inGt && iou > 0.0f;
        // r is only consumed on the hot path, or while the thread still
        // needs its zero candidate (zkey==0). Skip cosf otherwise.
        if (hot || zkey == 0ull) {
            float th = fabsf(ga - pa[a]);
            float r = ang_measure(rp, th);
            // Reference v = align*in_gts, align=(s*iou^5)*r^3, s>0, iou>=0.
            // v>0: positive (needs s). v==+0: zero candidate (index-ranked).
            // v<0 / -0: never selectable (>=13 +0 zeros exist per row).
            bool zeroCand;
            if (hot && r > 0.0f) {
                float s = sc[(size_t)a * C];   // scattered load, rare path only
                float v = align_fn(s, iou, r);
                if (v > 0.0f) {
                    zeroCand = false;
                    u64 key = ((u64)ford(v) << 32) | (u64)(0xFFFFFFFFu - (u32)a);
                    if (key > arr[TOPK - 1]) {
#pragma unroll
                        for (int jj = 0; jj < TOPK; jj++) {
                            u64 hi = arr[jj] > key ? arr[jj] : key;
                            u64 lo = arr[jj] > key ? key : arr[jj];
                            arr[jj] = hi;
                            key = lo;
                        }
                    }
                } else {
                    zeroCand = true;  // s==0 or iou^5 underflow -> v == +0 exactly
                }
            } else {
                zeroCand = (r >= 0.0f);  // v == sign(r)*0; only +0 selectable
            }
            if (zeroCand && zkey == 0ull) {
                zkey = (0x80000000ull << 32) | (u64)(0xFFFFFFFFu - (u32)a);
            }
        }
    }
    // merge the single zero candidate (provably sufficient per thread)
    if (zkey > arr[TOPK - 1]) {
        u64 key = zkey;
#pragma unroll
        for (int jj = 0; jj < TOPK; jj++) {
            u64 hi = arr[jj] > key ? arr[jj] : key;
            u64 lo = arr[jj] > key ? key : arr[jj];
            arr[jj] = hi;
            key = lo;
        }
    }

    // 13 rounds of block-wide max; wave shuffle + per-wave LDS slot
    __shared__ u64 sh[2][K1_THREADS / 64];
    int lane = tid & 63, wv = tid >> 6;
    for (int round = 0; round < TOPK; round++) {
        u64 head = arr[0];
        u64 m = head;
#pragma unroll
        for (int st = 32; st > 0; st >>= 1) {
            u64 o = __shfl_xor(m, st, 64);
            if (o > m) m = o;
        }
        if (lane == 0) sh[round & 1][wv] = m;
        __syncthreads();
        u64 win = sh[round & 1][0];
#pragma unroll
        for (int w = 1; w < K1_THREADS / 64; w++) {
            u64 o = sh[round & 1][w]; if (o > win) win = o;
        }
        if (head == win && win != 0ull) {  // unique key -> exactly one winner
#pragma unroll
            for (int jj = 0; jj < TOPK - 1; jj++) arr[jj] = arr[jj + 1];
            arr[TOPK - 1] = 0ull;
            int a = (int)(0xFFFFFFFFu - (u32)(win & 0xFFFFFFFFull));
            float2 apt = ac[a];
            float mnv = fminf(fminf(apt.x - g.x, apt.y - g.y), fminf(g.z - apt.x, g.w - apt.y));
            if (mnv > 1e-9f) {  // mask_pos = mask_topk * in_gts * mask_gt
                atomicAdd(&cnt[(size_t)b * A + a], 1);
                atomicMax(&assign1[(size_t)b * A + a], i);
            }
        }
    }
}

__global__ __launch_bounds__(256)
void k2_resolve(const float* __restrict__ scores, const float* __restrict__ pbox,
                const float* __restrict__ pang, const int* __restrict__ glab,
                const float* __restrict__ gbox, const float* __restrict__ gang,
                const int* __restrict__ cnt, const int* __restrict__ assign1,
                int* __restrict__ assign, float* __restrict__ alignv,
                u32* __restrict__ pam, u32* __restrict__ pov,
                int bs, int A, int n, int C) {
    int t = blockIdx.x * blockDim.x + threadIdx.x;
    if (t >= bs * A) return;
    int b = t / A;
    int c = cnt[t];
    int asg = -1;
    float alv = 0.0f;
    if (c > 0) {
        float4 p = ((const float4*)pbox)[t];
        if (c == 1) {
            asg = assign1[t];
        } else {
            // reference: overlaps.argmax(1) over ALL gt rows, first-max tie-break
            float best = -1.0f;
            asg = 0;
            for (int i = 0; i < n; i++) {
                float4 gi = ((const float4*)gbox)[b * n + i];
                float io = iou_fn(gi, p);
                if (io > best) { best = io; asg = i; }
            }
        }
        float4 g = ((const float4*)gbox)[b * n + asg];
        RowParams rp = row_params(g);
        float iou = iou_fn(g, p);
        float th = fabsf(gang[b * n + asg] - pang[t]);
        float r = ang_measure(rp, th);
        float s = scores[(size_t)t * C + glab[b * n + asg]];
        alv = align_fn(s, iou, r);
        atomicMax(&pam[b * n + asg], ford(alv));
        atomicMax(&pov[b * n + asg], ford(iou));
    }
    assign[t] = asg;
    alignv[t] = alv;
}

__global__ __launch_bounds__(256)
void k3_out(const int* __restrict__ glab, const float* __restrict__ gbox,
            const float* __restrict__ gang, const int* __restrict__ assign,
            const float* __restrict__ alignv, const u32* __restrict__ pam,
            const u32* __restrict__ pov, float* __restrict__ out,
            int bs, int A, int n, int C) {
    __shared__ float s_nv[256];
    __shared__ int s_lf[256];
    int tid = threadIdx.x;
    int base = blockIdx.x * 256;
    int t = base + tid;
    int BA = bs * A;

    if (t < BA) {
        int b = t / A;
        int asg = assign[t];
        bool fg = asg >= 0;
        int tgt = fg ? asg : 0;  // argmax of all-zero column -> row 0
        int lb = glab[b * n + tgt];
        if (lb < 0) lb = 0;

        float* o_tlab = out;
        float* o_tbb = out + BA;
        float* o_tang = out + (size_t)BA * 5;
        float* o_fg = out + (size_t)BA * 6 + (size_t)BA * C;

        o_tlab[t] = (float)lb;
        ((float4*)o_tbb)[t] = ((const float4*)gbox)[b * n + tgt];
        o_tang[t] = gang[b * n + tgt];
        o_fg[t] = fg ? 1.0f : 0.0f;

        float nv = 0.0f;
        if (fg) {
            float pamv = funord(pam[b * n + asg]);
            float povv = funord(pov[b * n + asg]);
            float vv = (alignv[t] * povv) / (pamv + 1e-9f);
            nv = fmaxf(vv, 0.0f);  // 59 other rows contribute exactly 0 to the max
        }
        s_nv[tid] = nv;
        s_lf[tid] = fg ? lb : -1;
    } else {
        s_nv[tid] = 0.0f;
        s_lf[tid] = -1;
    }
    __syncthreads();

    // ts: coalesced float4 writes, (anchor, class-quad) with quad fastest
    int Q = C / 4;  // 20
    int nA = min(256, BA - base);
    if (nA <= 0) return;
    int total = nA * Q;
    float4* o_ts = (float4*)(out + (size_t)BA * 6) + (size_t)base * Q;
    for (int idx = tid; idx < total; idx += 256) {
        int tl = idx / Q;
        int q = idx - tl * Q;
        float nv = s_nv[tl];
        int lf = s_lf[tl];
        int cb = q * 4;
        float4 o;
        o.x = (lf == cb) ? nv : 0.0f;
        o.y = (lf == cb + 1) ? nv : 0.0f;
        o.z = (lf == cb + 2) ? nv : 0.0f;
        o.w = (lf == cb + 3) ? nv : 0.0f;
        o_ts[idx] = o;
    }
}

extern "C" void kernel_launch(void* const* d_in, const int* in_sizes, int n_in,
                              void* d_out, int out_size, void* d_ws, size_t ws_size,
                              hipStream_t stream) {
    const float* scores = (const float*)d_in[0];
    const float* pbox = (const float*)d_in[1];
    const float* pang = (const float*)d_in[2];
    const float* anc = (const float*)d_in[3];
    const int* glab = (const int*)d_in[4];
    const float* gbox = (const float*)d_in[5];
    const float* gang = (const float*)d_in[6];
    const float* mgt = (const float*)d_in[7];

    const int C = 80;
    int A = in_sizes[3] / 2;
    int bs = in_sizes[0] / (A * C);
    int n = in_sizes[4] / bs;
    int BA = bs * A;
    int BN = bs * n;

    char* ws = (char*)d_ws;
    int* cnt = (int*)ws;        ws += sizeof(int) * (size_t)BA;
    int* assign1 = (int*)ws;    ws += sizeof(int) * (size_t)BA;
    int* assign = (int*)ws;     ws += sizeof(int) * (size_t)BA;
    float* alignv = (float*)ws; ws += sizeof(float) * (size_t)BA;
    u32* pam = (u32*)ws;        ws += sizeof(u32) * (size_t)BN;
    u32* pov = (u32*)ws;        ws += sizeof(u32) * (size_t)BN;

    k0_init<<<(BA + 255) / 256, 256, 0, stream>>>(cnt, assign1, pam, pov, BA, BN);
    k1_topk<<<BN, K1_THREADS, 0, stream>>>(scores, pbox, pang, anc, glab, gbox, gang, mgt,
                                           cnt, assign1, bs, A, n, C);
    k2_resolve<<<(BA + 255) / 256, 256, 0, stream>>>(scores, pbox, pang, glab, gbox, gang,
                                                     cnt, assign1, assign, alignv, pam, pov,
                                                     bs, A, n, C);
    k3_out<<<(BA + 255) / 256, 256, 0, stream>>>(glab, gbox, gang, assign, alignv, pam, pov,
                                                 (float*)d_out, bs, A, n, C);
}